// Round 9
// baseline (666.116 us; speedup 1.0000x reference)
//
#include <hip/hip_runtime.h>
#include <math.h>

#define NN 30000
#define NE 480000
#define NG 512

#define INV_SQRT_NN 0.5129891760425771f   // 1/sqrt(3.8)
#define INV_SQRT3   0.5773502691896258f   // 1/sqrt(3)
#define SCALE_W2    0.0625f               // 1/sqrt(256)
#define RAD_C       14.607377f            // 1.14136*e^2*sqrt(3)

typedef __bf16 bf16x8 __attribute__((ext_vector_type(8)));
typedef float f32x4 __attribute__((ext_vector_type(4)));
typedef unsigned short ushort8 __attribute__((ext_vector_type(8)));

__device__ __forceinline__ unsigned short f2bf(float f) {
  unsigned int u = __float_as_uint(f);
  return (unsigned short)((u + 0x7FFFu + ((u >> 16) & 1u)) >> 16);  // RNE
}

// ---------------------------------------------------------------------------
// K1: per-edge geometry -> sh(E,16), scal(E,4), x0 += sh (LDS-transposed scatter)
// ---------------------------------------------------------------------------
__global__ __launch_bounds__(256) void k_edge(
    const float* __restrict__ pos,
    const int* __restrict__ esrc,
    const int* __restrict__ edst,
    float* __restrict__ shg,
    float* __restrict__ scalg,
    float* __restrict__ x0) {
  __shared__ float S_lds[256*17];
  __shared__ int   d_lds[256];
  const int t = threadIdx.x;
  const int e = blockIdx.x * 256 + t;
  int s = esrc[e], d = edst[e];
  float ex = pos[3*s]   - pos[3*d];
  float ey = pos[3*s+1] - pos[3*d+1];
  float ez = pos[3*s+2] - pos[3*d+2];
  float r = sqrtf(ex*ex + ey*ey + ez*ez);
  float inv = 1.0f / fmaxf(r, 1e-9f);
  float x = ex*inv, y = ey*inv, z = ez*inv;
  float x2 = x*x, y2 = y*y, z2 = z*z;
  float S[16];
  S[0]  = 1.0f;
  S[1]  = 1.7320508075688772f * x;
  S[2]  = 1.7320508075688772f * y;
  S[3]  = 1.7320508075688772f * z;
  S[4]  = 3.872983346207417f * x * y;
  S[5]  = 3.872983346207417f * y * z;
  S[6]  = 1.118033988749895f * (3.0f*z2 - 1.0f);
  S[7]  = 3.872983346207417f * x * z;
  S[8]  = 1.9364916731037085f * (x2 - y2);
  S[9]  = 2.091650066335189f  * y * (3.0f*x2 - y2);
  S[10] = 10.246950765959598f * x * y * z;
  S[11] = 1.6201851746019651f * y * (5.0f*z2 - 1.0f);
  S[12] = 1.3228756555322954f * z * (5.0f*z2 - 3.0f);
  S[13] = 1.6201851746019651f * x * (5.0f*z2 - 1.0f);
  S[14] = 5.123475382979799f  * z * (x2 - y2);
  S[15] = 2.091650066335189f  * x * (x2 - y2);
  float4* shv = (float4*)(shg + (size_t)e * 16);
  shv[0] = make_float4(S[0],  S[1],  S[2],  S[3]);
  shv[1] = make_float4(S[4],  S[5],  S[6],  S[7]);
  shv[2] = make_float4(S[8],  S[9],  S[10], S[11]);
  shv[3] = make_float4(S[12], S[13], S[14], S[15]);
  float sc[3];
  #pragma unroll
  for (int c = 0; c < 3; ++c) {
    float v = 0.5f + (float)c;
    float uu = r - v;
    float dd = uu*uu - 1.0f;
    sc[c] = (dd < 0.0f) ? RAD_C * expf(1.0f/dd) : 0.0f;
  }
  ((float4*)scalg)[e] = make_float4(sc[0], sc[1], sc[2], 0.0f);

  d_lds[t] = d;
  #pragma unroll
  for (int j = 0; j < 16; ++j) S_lds[t*17 + j] = S[j];
  __syncthreads();
  #pragma unroll
  for (int it = 0; it < 16; ++it) {
    int idx = it*256 + t;
    int el = idx >> 4, j = idx & 15;
    atomicAdd(&x0[(size_t)d_lds[el]*16 + j], S_lds[el*17 + j]);
  }
}

// ---------------------------------------------------------------------------
// K_prep: convert all B-matrices to MFMA-fragment-ordered bf16 (unchanged).
// ---------------------------------------------------------------------------
__global__ void k_prep(const float* __restrict__ W2a, const float* __restrict__ cg1,
                       const float* __restrict__ cg2, const float* __restrict__ W2b,
                       unsigned short* __restrict__ Bcg, unsigned short* __restrict__ Bw2,
                       unsigned short* __restrict__ Bc2, unsigned short* __restrict__ Bw2b) {
  int tid = blockIdx.x * 256 + threadIdx.x;
  if (tid >= 12544) return;
  if (tid < 10240) {
    int sel = tid >= 5120;
    int t = sel ? tid - 5120 : tid;
    int lane = t & 63;
    int kc = (t >> 6) & 7;
    int nt = t >> 9;
    int n  = nt*16 + (lane & 15);
    int kb = kc*32 + (lane >> 4)*8;
    ushort8 v;
    if (!sel) {
      #pragma unroll
      for (int j = 0; j < 8; ++j) v[j] = f2bf(cg1[n*256 + kb + j]);
      *(ushort8*)&Bcg[(size_t)t*8] = v;
    } else {
      #pragma unroll
      for (int j = 0; j < 8; ++j) v[j] = f2bf(W2a[(kb + j)*160 + n] * SCALE_W2);
      *(ushort8*)&Bw2[(size_t)t*8] = v;
    }
  } else if (tid < 12032) {
    int et = tid - 10240;
    int L = et & 63;
    int kc = (et >> 6) & 3;
    int nt = et >> 8;
    int mcol = L & 15;
    int ib = kc*32 + (L >> 4)*8;
    ushort8 v;
    #pragma unroll
    for (int jj = 0; jj < 8; ++jj) v[jj] = f2bf(cg2[nt*2048 + (ib + jj)*16 + mcol]);
    *(ushort8*)&Bc2[(size_t)et*8] = v;
  } else {
    int et = tid - 12032;
    int L = et & 63;
    int kc = et >> 6;
    int mcol = L & 15;
    int ib = kc*32 + (L >> 4)*8;
    ushort8 v;
    #pragma unroll
    for (int jj = 0; jj < 8; ++jj)
      v[jj] = (mcol < 7) ? f2bf(W2b[(ib + jj)*7 + mcol] * SCALE_W2) : (unsigned short)0;
    *(ushort8*)&Bw2b[(size_t)et*8] = v;
  }
}

// ---------------------------------------------------------------------------
// K2: fused MLP1 + conv1 via MFMA.  Single-buffered 20KB LDS B-panels
// (2 barriers/kc) -> LDS/block 30.7KB -> 5 blocks/CU for latency hiding.
// Global B prefetch still issued a full kc ahead.
// ---------------------------------------------------------------------------
__global__ __launch_bounds__(256, 4) void k_conv1(
    const float* __restrict__ x0, const float* __restrict__ shg,
    const float* __restrict__ scalg,
    const int* __restrict__ esrc, const int* __restrict__ edst,
    const float* __restrict__ W1a,
    const unsigned short* __restrict__ Bcg, const unsigned short* __restrict__ Bw2,
    float* __restrict__ x1) {
  __shared__ float sh_lds[64*20];
  __shared__ float xs_lds[64*20];
  __shared__ unsigned short Bpan[20*512];   // 20 panels x 1KB = 20KB single buffer
  const int t = threadIdx.x;
  const int e0 = blockIdx.x * 64;

  {
    int e = t >> 2, q = t & 3;
    int ge = e0 + e;
    *(float4*)&sh_lds[e*20 + q*4] = ((const float4*)shg)[(size_t)ge*4 + q];
    float4 xv = ((const float4*)x0)[(size_t)esrc[ge]*4 + q];
    xv.x *= INV_SQRT_NN; xv.y *= INV_SQRT_NN; xv.z *= INV_SQRT_NN; xv.w *= INV_SQRT_NN;
    *(float4*)&xs_lds[e*20 + q*4] = xv;
  }
  const int L  = t & 63;
  const int wv = t >> 6;
  const int m  = L & 15;
  const int q4 = L >> 4;
  const int j0 = (q4 & 1) * 8;
  const int p  = q4 >> 1;
  const int el = wv*16 + m;

  const unsigned short* psrc[5];
  #pragma unroll
  for (int i = 0; i < 5; ++i) {
    int pnl = wv*5 + i;
    int g = pnl >= 10;
    int nt = g ? pnl - 10 : pnl;
    psrc[i] = (g ? Bw2 : Bcg) + (((size_t)nt*8)*64 + L)*8;
  }

  float4 sc = ((const float4*)scalg)[e0 + el];
  const float hs0 = sc.x*INV_SQRT3, hs1 = sc.y*INV_SQRT3, hs2 = sc.z*INV_SQRT3;

  ushort8 pf[5];
  #pragma unroll
  for (int i = 0; i < 5; ++i) pf[i] = *(const ushort8*)psrc[i];
  #pragma unroll
  for (int i = 0; i < 5; ++i) *(ushort8*)&Bpan[(wv*5 + i)*512 + L*8] = pf[i];
  __syncthreads();

  float sh8[8];
  *(float4*)&sh8[0] = *(float4*)&sh_lds[el*20 + j0];
  *(float4*)&sh8[4] = *(float4*)&sh_lds[el*20 + j0 + 4];
  float xsc[8];
  #pragma unroll
  for (int kc = 0; kc < 8; ++kc) xsc[kc] = xs_lds[el*20 + kc*2 + p];

  f32x4 ac[10], aw[10];
  #pragma unroll
  for (int i = 0; i < 10; ++i) {
    ac[i] = (f32x4)(0.0f);
    aw[i] = (f32x4)(0.0f);
  }

  #pragma unroll
  for (int kc = 0; kc < 8; ++kc) {
    // issue next-kc global prefetch early (hides L2 latency under compute)
    if (kc < 7) {
      #pragma unroll
      for (int i = 0; i < 5; ++i) pf[i] = *(const ushort8*)(psrc[i] + (size_t)(kc+1)*512);
    }
    float xc = xsc[kc];
    ushort8 ao;
    #pragma unroll
    for (int j = 0; j < 8; ++j) ao[j] = f2bf(xc * sh8[j]);
    int mh = kc*32 + q4*8;
    float4 w0a = *(const float4*)&W1a[mh];
    float4 w0b = *(const float4*)&W1a[mh + 4];
    float4 w1a = *(const float4*)&W1a[256 + mh];
    float4 w1b = *(const float4*)&W1a[256 + mh + 4];
    float4 w2a = *(const float4*)&W1a[512 + mh];
    float4 w2b = *(const float4*)&W1a[512 + mh + 4];
    ushort8 ah;
    ah[0] = f2bf(fmaxf(hs0*w0a.x + hs1*w1a.x + hs2*w2a.x, 0.0f));
    ah[1] = f2bf(fmaxf(hs0*w0a.y + hs1*w1a.y + hs2*w2a.y, 0.0f));
    ah[2] = f2bf(fmaxf(hs0*w0a.z + hs1*w1a.z + hs2*w2a.z, 0.0f));
    ah[3] = f2bf(fmaxf(hs0*w0a.w + hs1*w1a.w + hs2*w2a.w, 0.0f));
    ah[4] = f2bf(fmaxf(hs0*w0b.x + hs1*w1b.x + hs2*w2b.x, 0.0f));
    ah[5] = f2bf(fmaxf(hs0*w0b.y + hs1*w1b.y + hs2*w2b.y, 0.0f));
    ah[6] = f2bf(fmaxf(hs0*w0b.z + hs1*w1b.z + hs2*w2b.z, 0.0f));
    ah[7] = f2bf(fmaxf(hs0*w0b.w + hs1*w1b.w + hs2*w2b.w, 0.0f));
    bf16x8 aoB = __builtin_bit_cast(bf16x8, ao);
    bf16x8 ahB = __builtin_bit_cast(bf16x8, ah);
    #pragma unroll
    for (int nt = 0; nt < 10; ++nt) {
      ushort8 b1 = *(const ushort8*)&Bpan[nt*512 + L*8];
      ushort8 b2 = *(const ushort8*)&Bpan[(10 + nt)*512 + L*8];
      ac[nt] = __builtin_amdgcn_mfma_f32_16x16x32_bf16(aoB, __builtin_bit_cast(bf16x8, b1), ac[nt], 0, 0, 0);
      aw[nt] = __builtin_amdgcn_mfma_f32_16x16x32_bf16(ahB, __builtin_bit_cast(bf16x8, b2), aw[nt], 0, 0, 0);
    }
    if (kc < 7) {
      __syncthreads();   // all waves done reading Bpan for kc
      #pragma unroll
      for (int i = 0; i < 5; ++i) *(ushort8*)&Bpan[(wv*5 + i)*512 + L*8] = pf[i];
      __syncthreads();   // kc+1 panels visible
    }
  }

  int ebase = e0 + wv*16 + q4*4;
  int d0 = edst[ebase], d1 = edst[ebase+1], d2 = edst[ebase+2], d3 = edst[ebase+3];
  #pragma unroll
  for (int nt = 0; nt < 10; ++nt) {
    int col = nt*16 + m;
    atomicAdd(&x1[(size_t)d0*160 + col], ac[nt][0]*aw[nt][0]*INV_SQRT_NN);
    atomicAdd(&x1[(size_t)d1*160 + col], ac[nt][1]*aw[nt][1]*INV_SQRT_NN);
    atomicAdd(&x1[(size_t)d2*160 + col], ac[nt][2]*aw[nt][2]*INV_SQRT_NN);
    atomicAdd(&x1[(size_t)d3*160 + col], ac[nt][3]*aw[nt][3]*INV_SQRT_NN);
  }
}

// ---------------------------------------------------------------------------
// K3: gate  x1(N,160) -> x2bf(N,128) in bf16
// ---------------------------------------------------------------------------
__device__ __forceinline__ float gate_val(const float* xr, int o) {
  if (o < 16) return fmaxf(xr[o], 0.0f);
  if (o < 32) return fabsf(xr[o]);
  int oo = o - 32;
  int vi = oo / 3;
  float g = xr[32 + vi];
  g = (vi & 8) ? tanhf(g) : fmaxf(g, 0.0f);
  return xr[64 + oo] * g;
}

__global__ void k_gate(const float* __restrict__ x1, unsigned short* __restrict__ x2b) {
  int tid = blockIdx.x * 256 + threadIdx.x;
  if (tid >= NN*64) return;
  int n = tid >> 6, o2 = (tid & 63) * 2;
  const float* xr = x1 + (size_t)n * 160;
  ushort2 st;
  st.x = f2bf(gate_val(xr, o2));
  st.y = f2bf(gate_val(xr, o2 + 1));
  *(ushort2*)&x2b[(size_t)n*128 + o2] = st;
}

// ---------------------------------------------------------------------------
// K4: fused MLP2 + conv2 via MFMA (round-7 version: direct L2 B loads,
// launch_bounds 4 -- the LDS-staged variant was neutral/negative, reverted).
// ---------------------------------------------------------------------------
__global__ __launch_bounds__(256, 4) void k_conv2(
    const unsigned short* __restrict__ x2b, const float* __restrict__ shg,
    const float* __restrict__ scalg,
    const int* __restrict__ esrc, const int* __restrict__ edst,
    const float* __restrict__ W1b,
    const unsigned short* __restrict__ Bc2, const unsigned short* __restrict__ Bw2b,
    float* __restrict__ x3) {
  __shared__ float sh_lds[64*20];
  const int t = threadIdx.x;
  const int e0 = blockIdx.x * 64;
  {
    int e = t >> 2, q = t & 3;
    *(float4*)&sh_lds[e*20 + q*4] = ((const float4*)shg)[(size_t)(e0 + e)*4 + q];
  }
  __syncthreads();

  const int L = t & 63, wv = t >> 6;
  const int m = L & 15, q4 = L >> 4;
  const int el = wv*16 + m;
  const int ge = e0 + el;
  const int s_el = esrc[ge];
  float4 sc = ((const float4*)scalg)[ge];
  const float hs0 = sc.x*INV_SQRT3, hs1 = sc.y*INV_SQRT3, hs2 = sc.z*INV_SQRT3;

  f32x4 tAcc[7];
  #pragma unroll
  for (int nt = 0; nt < 7; ++nt) tAcc[nt] = (f32x4)(0.0f);
  f32x4 wAcc = (f32x4)(0.0f);

  const unsigned short* arow = x2b + (size_t)s_el*128 + q4*8;
  #pragma unroll
  for (int kc = 0; kc < 4; ++kc) {
    ushort8 a = *(const ushort8*)&arow[kc*32];
    bf16x8 aB = __builtin_bit_cast(bf16x8, a);
    #pragma unroll
    for (int nt = 0; nt < 7; ++nt) {
      ushort8 b = *(const ushort8*)&Bc2[(((size_t)nt*4 + kc)*64 + L)*8];
      tAcc[nt] = __builtin_amdgcn_mfma_f32_16x16x32_bf16(aB, __builtin_bit_cast(bf16x8, b), tAcc[nt], 0, 0, 0);
    }
  }
  #pragma unroll
  for (int kc = 0; kc < 8; ++kc) {
    int mh = kc*32 + q4*8;
    float4 w0a = *(const float4*)&W1b[mh];
    float4 w0b = *(const float4*)&W1b[mh + 4];
    float4 w1a = *(const float4*)&W1b[256 + mh];
    float4 w1b = *(const float4*)&W1b[256 + mh + 4];
    float4 w2a = *(const float4*)&W1b[512 + mh];
    float4 w2b = *(const float4*)&W1b[512 + mh + 4];
    ushort8 ah;
    ah[0] = f2bf(fmaxf(hs0*w0a.x + hs1*w1a.x + hs2*w2a.x, 0.0f));
    ah[1] = f2bf(fmaxf(hs0*w0a.y + hs1*w1a.y + hs2*w2a.y, 0.0f));
    ah[2] = f2bf(fmaxf(hs0*w0a.z + hs1*w1a.z + hs2*w2a.z, 0.0f));
    ah[3] = f2bf(fmaxf(hs0*w0a.w + hs1*w1a.w + hs2*w2a.w, 0.0f));
    ah[4] = f2bf(fmaxf(hs0*w0b.x + hs1*w1b.x + hs2*w2b.x, 0.0f));
    ah[5] = f2bf(fmaxf(hs0*w0b.y + hs1*w1b.y + hs2*w2b.y, 0.0f));
    ah[6] = f2bf(fmaxf(hs0*w0b.z + hs1*w1b.z + hs2*w2b.z, 0.0f));
    ah[7] = f2bf(fmaxf(hs0*w0b.w + hs1*w1b.w + hs2*w2b.w, 0.0f));
    ushort8 b = *(const ushort8*)&Bw2b[((size_t)kc*64 + L)*8];
    wAcc = __builtin_amdgcn_mfma_f32_16x16x32_bf16(
        __builtin_bit_cast(bf16x8, ah), __builtin_bit_cast(bf16x8, b), wAcc, 0, 0, 0);
  }

  int dsts[4];
  #pragma unroll
  for (int r = 0; r < 4; ++r) dsts[r] = edst[e0 + wv*16 + q4*4 + r];
  float ef[4] = {0.f, 0.f, 0.f, 0.f};
  #pragma unroll
  for (int nt = 0; nt < 7; ++nt) {
    #pragma unroll
    for (int r = 0; r < 4; ++r) {
      float v = tAcc[nt][r] * sh_lds[(wv*16 + q4*4 + r)*20 + m];
      v += __shfl_xor(v, 1);
      v += __shfl_xor(v, 2);
      v += __shfl_xor(v, 4);
      v += __shfl_xor(v, 8);
      if (m == nt) ef[r] = v;
    }
  }
  if (m < 7) {
    #pragma unroll
    for (int r = 0; r < 4; ++r)
      atomicAdd(&x3[(size_t)dsts[r]*7 + m], ef[r] * wAcc[r] * INV_SQRT_NN);
  }
}

// ---------------------------------------------------------------------------
// K5: graph readout  out[batch[n]] += x3[n] * 0.5
// ---------------------------------------------------------------------------
__global__ void k_out(const float* __restrict__ x3, const int* __restrict__ batch,
                      float* __restrict__ out) {
  int tid = blockIdx.x * 256 + threadIdx.x;
  if (tid >= NN*7) return;
  int n = tid / 7;
  int k = tid - n*7;
  atomicAdd(&out[batch[n]*7 + k], x3[tid] * 0.5f);
}

extern "C" void kernel_launch(void* const* d_in, const int* in_sizes, int n_in,
                              void* d_out, int out_size, void* d_ws, size_t ws_size,
                              hipStream_t stream) {
  const float* pos  = (const float*)d_in[0];
  const float* W1a  = (const float*)d_in[1];
  const float* W2a  = (const float*)d_in[2];
  const float* cg1  = (const float*)d_in[3];
  const float* W1b  = (const float*)d_in[4];
  const float* W2b  = (const float*)d_in[5];
  const float* cg2  = (const float*)d_in[6];
  const int* esrc   = (const int*)d_in[7];
  const int* edst   = (const int*)d_in[8];
  const int* batch  = (const int*)d_in[9];
  float* out = (float*)d_out;

  float* ws    = (float*)d_ws;
  float* shg   = ws;                       // NE*16
  float* scalg = shg   + (size_t)NE*16;    // NE*4
  float* x0    = scalg + (size_t)NE*4;     // NN*16
  float* x1    = x0    + (size_t)NN*16;    // NN*160
  float* x2g   = x1    + (size_t)NN*160;   // NN*128 slot (bf16 used)
  float* x3    = x2g   + (size_t)NN*128;   // NN*7
  unsigned short* x2b  = (unsigned short*)x2g;
  unsigned short* Bcg  = (unsigned short*)(x3 + (size_t)NN*7);  // 40960 bf16
  unsigned short* Bw2  = Bcg + 40960;                           // 40960 bf16
  unsigned short* Bc2  = Bw2 + 40960;                           // 14336 bf16
  unsigned short* Bw2b = Bc2 + 14336;                           // 4096 bf16

  hipMemsetAsync(x0, 0, sizeof(float)*(size_t)NN*16, stream);
  hipMemsetAsync(x1, 0, sizeof(float)*(size_t)NN*160, stream);
  hipMemsetAsync(x3, 0, sizeof(float)*(size_t)NN*7, stream);
  hipMemsetAsync(d_out, 0, sizeof(float)*NG*7, stream);

  k_prep <<<49, 256, 0, stream>>>(W2a, cg1, cg2, W2b, Bcg, Bw2, Bc2, Bw2b);
  k_edge <<<NE/256, 256, 0, stream>>>(pos, esrc, edst, shg, scalg, x0);
  k_conv1<<<NE/64, 256, 0, stream>>>(x0, shg, scalg, esrc, edst, W1a, Bcg, Bw2, x1);
  k_gate <<<(NN*64)/256, 256, 0, stream>>>(x1, x2b);
  k_conv2<<<NE/64, 256, 0, stream>>>(x2b, shg, scalg, esrc, edst, W1b, Bc2, Bw2b, x3);
  k_out  <<<(NN*7 + 255)/256, 256, 0, stream>>>(x3, batch, out);
}

// Round 10
// 510.708 us; speedup vs baseline: 1.3043x; 1.3043x over previous
//
#include <hip/hip_runtime.h>
#include <math.h>

#define NN 30000
#define NE 480000
#define NG 512

#define INV_SQRT_NN 0.5129891760425771f   // 1/sqrt(3.8)
#define INV_SQRT3   0.5773502691896258f   // 1/sqrt(3)
#define SCALE_W2    0.0625f               // 1/sqrt(256)
#define RAD_C       14.607377f            // 1.14136*e^2*sqrt(3)

typedef __bf16 bf16x8 __attribute__((ext_vector_type(8)));
typedef float f32x4 __attribute__((ext_vector_type(4)));
typedef unsigned short ushort8 __attribute__((ext_vector_type(8)));

__device__ __forceinline__ unsigned short f2bf(float f) {
  unsigned int u = __float_as_uint(f);
  return (unsigned short)((u + 0x7FFFu + ((u >> 16) & 1u)) >> 16);  // RNE
}

// ---------------------------------------------------------------------------
// K1: per-edge geometry -> sh(E,16), scal(E,4), x0 += sh (LDS-transposed scatter)
// ---------------------------------------------------------------------------
__global__ __launch_bounds__(256) void k_edge(
    const float* __restrict__ pos,
    const int* __restrict__ esrc,
    const int* __restrict__ edst,
    float* __restrict__ shg,
    float* __restrict__ scalg,
    float* __restrict__ x0) {
  __shared__ float S_lds[256*17];
  __shared__ int   d_lds[256];
  const int t = threadIdx.x;
  const int e = blockIdx.x * 256 + t;
  int s = esrc[e], d = edst[e];
  float ex = pos[3*s]   - pos[3*d];
  float ey = pos[3*s+1] - pos[3*d+1];
  float ez = pos[3*s+2] - pos[3*d+2];
  float r = sqrtf(ex*ex + ey*ey + ez*ez);
  float inv = 1.0f / fmaxf(r, 1e-9f);
  float x = ex*inv, y = ey*inv, z = ez*inv;
  float x2 = x*x, y2 = y*y, z2 = z*z;
  float S[16];
  S[0]  = 1.0f;
  S[1]  = 1.7320508075688772f * x;
  S[2]  = 1.7320508075688772f * y;
  S[3]  = 1.7320508075688772f * z;
  S[4]  = 3.872983346207417f * x * y;
  S[5]  = 3.872983346207417f * y * z;
  S[6]  = 1.118033988749895f * (3.0f*z2 - 1.0f);
  S[7]  = 3.872983346207417f * x * z;
  S[8]  = 1.9364916731037085f * (x2 - y2);
  S[9]  = 2.091650066335189f  * y * (3.0f*x2 - y2);
  S[10] = 10.246950765959598f * x * y * z;
  S[11] = 1.6201851746019651f * y * (5.0f*z2 - 1.0f);
  S[12] = 1.3228756555322954f * z * (5.0f*z2 - 3.0f);
  S[13] = 1.6201851746019651f * x * (5.0f*z2 - 1.0f);
  S[14] = 5.123475382979799f  * z * (x2 - y2);
  S[15] = 2.091650066335189f  * x * (x2 - y2);
  float4* shv = (float4*)(shg + (size_t)e * 16);
  shv[0] = make_float4(S[0],  S[1],  S[2],  S[3]);
  shv[1] = make_float4(S[4],  S[5],  S[6],  S[7]);
  shv[2] = make_float4(S[8],  S[9],  S[10], S[11]);
  shv[3] = make_float4(S[12], S[13], S[14], S[15]);
  float sc[3];
  #pragma unroll
  for (int c = 0; c < 3; ++c) {
    float v = 0.5f + (float)c;
    float uu = r - v;
    float dd = uu*uu - 1.0f;
    sc[c] = (dd < 0.0f) ? RAD_C * expf(1.0f/dd) : 0.0f;
  }
  ((float4*)scalg)[e] = make_float4(sc[0], sc[1], sc[2], 0.0f);

  d_lds[t] = d;
  #pragma unroll
  for (int j = 0; j < 16; ++j) S_lds[t*17 + j] = S[j];
  __syncthreads();
  #pragma unroll
  for (int it = 0; it < 16; ++it) {
    int idx = it*256 + t;
    int el = idx >> 4, j = idx & 15;
    atomicAdd(&x0[(size_t)d_lds[el]*16 + j], S_lds[el*17 + j]);
  }
}

// ---------------------------------------------------------------------------
// K_prep: convert all B-matrices to MFMA-fragment-ordered bf16 (unchanged).
// ---------------------------------------------------------------------------
__global__ void k_prep(const float* __restrict__ W2a, const float* __restrict__ cg1,
                       const float* __restrict__ cg2, const float* __restrict__ W2b,
                       unsigned short* __restrict__ Bcg, unsigned short* __restrict__ Bw2,
                       unsigned short* __restrict__ Bc2, unsigned short* __restrict__ Bw2b) {
  int tid = blockIdx.x * 256 + threadIdx.x;
  if (tid >= 12544) return;
  if (tid < 10240) {
    int sel = tid >= 5120;
    int t = sel ? tid - 5120 : tid;
    int lane = t & 63;
    int kc = (t >> 6) & 7;
    int nt = t >> 9;
    int n  = nt*16 + (lane & 15);
    int kb = kc*32 + (lane >> 4)*8;
    ushort8 v;
    if (!sel) {
      #pragma unroll
      for (int j = 0; j < 8; ++j) v[j] = f2bf(cg1[n*256 + kb + j]);
      *(ushort8*)&Bcg[(size_t)t*8] = v;
    } else {
      #pragma unroll
      for (int j = 0; j < 8; ++j) v[j] = f2bf(W2a[(kb + j)*160 + n] * SCALE_W2);
      *(ushort8*)&Bw2[(size_t)t*8] = v;
    }
  } else if (tid < 12032) {
    int et = tid - 10240;
    int L = et & 63;
    int kc = (et >> 6) & 3;
    int nt = et >> 8;
    int mcol = L & 15;
    int ib = kc*32 + (L >> 4)*8;
    ushort8 v;
    #pragma unroll
    for (int jj = 0; jj < 8; ++jj) v[jj] = f2bf(cg2[nt*2048 + (ib + jj)*16 + mcol]);
    *(ushort8*)&Bc2[(size_t)et*8] = v;
  } else {
    int et = tid - 12032;
    int L = et & 63;
    int kc = et >> 6;
    int mcol = L & 15;
    int ib = kc*32 + (L >> 4)*8;
    ushort8 v;
    #pragma unroll
    for (int jj = 0; jj < 8; ++jj)
      v[jj] = (mcol < 7) ? f2bf(W2b[(ib + jj)*7 + mcol] * SCALE_W2) : (unsigned short)0;
    *(ushort8*)&Bw2b[(size_t)et*8] = v;
  }
}

// ---------------------------------------------------------------------------
// K2: fused MLP1 + conv1 via MFMA.  Single-buffered 20KB LDS B-panels
// (30.7KB LDS/block -> 5 blocks/CU) with launch_bounds(256,2) so the
// register allocator keeps the spill-free 84-VGPR budget (round-9's (256,4)
// clamped VGPR to 64 and spilled: WRITE 300MB->1.4GB).
// ---------------------------------------------------------------------------
__global__ __launch_bounds__(256, 2) void k_conv1(
    const float* __restrict__ x0, const float* __restrict__ shg,
    const float* __restrict__ scalg,
    const int* __restrict__ esrc, const int* __restrict__ edst,
    const float* __restrict__ W1a,
    const unsigned short* __restrict__ Bcg, const unsigned short* __restrict__ Bw2,
    float* __restrict__ x1) {
  __shared__ float sh_lds[64*20];
  __shared__ float xs_lds[64*20];
  __shared__ unsigned short Bpan[20*512];   // 20 panels x 1KB = 20KB single buffer
  const int t = threadIdx.x;
  const int e0 = blockIdx.x * 64;

  {
    int e = t >> 2, q = t & 3;
    int ge = e0 + e;
    *(float4*)&sh_lds[e*20 + q*4] = ((const float4*)shg)[(size_t)ge*4 + q];
    float4 xv = ((const float4*)x0)[(size_t)esrc[ge]*4 + q];
    xv.x *= INV_SQRT_NN; xv.y *= INV_SQRT_NN; xv.z *= INV_SQRT_NN; xv.w *= INV_SQRT_NN;
    *(float4*)&xs_lds[e*20 + q*4] = xv;
  }
  const int L  = t & 63;
  const int wv = t >> 6;
  const int m  = L & 15;
  const int q4 = L >> 4;
  const int j0 = (q4 & 1) * 8;
  const int p  = q4 >> 1;
  const int el = wv*16 + m;

  const unsigned short* psrc[5];
  #pragma unroll
  for (int i = 0; i < 5; ++i) {
    int pnl = wv*5 + i;
    int g = pnl >= 10;
    int nt = g ? pnl - 10 : pnl;
    psrc[i] = (g ? Bw2 : Bcg) + (((size_t)nt*8)*64 + L)*8;
  }

  float4 sc = ((const float4*)scalg)[e0 + el];
  const float hs0 = sc.x*INV_SQRT3, hs1 = sc.y*INV_SQRT3, hs2 = sc.z*INV_SQRT3;

  ushort8 pf[5];
  #pragma unroll
  for (int i = 0; i < 5; ++i) pf[i] = *(const ushort8*)psrc[i];
  #pragma unroll
  for (int i = 0; i < 5; ++i) *(ushort8*)&Bpan[(wv*5 + i)*512 + L*8] = pf[i];
  __syncthreads();

  float sh8[8];
  *(float4*)&sh8[0] = *(float4*)&sh_lds[el*20 + j0];
  *(float4*)&sh8[4] = *(float4*)&sh_lds[el*20 + j0 + 4];
  float xsc[8];
  #pragma unroll
  for (int kc = 0; kc < 8; ++kc) xsc[kc] = xs_lds[el*20 + kc*2 + p];

  f32x4 ac[10], aw[10];
  #pragma unroll
  for (int i = 0; i < 10; ++i) {
    ac[i] = (f32x4)(0.0f);
    aw[i] = (f32x4)(0.0f);
  }

  #pragma unroll
  for (int kc = 0; kc < 8; ++kc) {
    // issue next-kc global prefetch early (hides L2 latency under compute)
    if (kc < 7) {
      #pragma unroll
      for (int i = 0; i < 5; ++i) pf[i] = *(const ushort8*)(psrc[i] + (size_t)(kc+1)*512);
    }
    float xc = xsc[kc];
    ushort8 ao;
    #pragma unroll
    for (int j = 0; j < 8; ++j) ao[j] = f2bf(xc * sh8[j]);
    int mh = kc*32 + q4*8;
    float4 w0a = *(const float4*)&W1a[mh];
    float4 w0b = *(const float4*)&W1a[mh + 4];
    float4 w1a = *(const float4*)&W1a[256 + mh];
    float4 w1b = *(const float4*)&W1a[256 + mh + 4];
    float4 w2a = *(const float4*)&W1a[512 + mh];
    float4 w2b = *(const float4*)&W1a[512 + mh + 4];
    ushort8 ah;
    ah[0] = f2bf(fmaxf(hs0*w0a.x + hs1*w1a.x + hs2*w2a.x, 0.0f));
    ah[1] = f2bf(fmaxf(hs0*w0a.y + hs1*w1a.y + hs2*w2a.y, 0.0f));
    ah[2] = f2bf(fmaxf(hs0*w0a.z + hs1*w1a.z + hs2*w2a.z, 0.0f));
    ah[3] = f2bf(fmaxf(hs0*w0a.w + hs1*w1a.w + hs2*w2a.w, 0.0f));
    ah[4] = f2bf(fmaxf(hs0*w0b.x + hs1*w1b.x + hs2*w2b.x, 0.0f));
    ah[5] = f2bf(fmaxf(hs0*w0b.y + hs1*w1b.y + hs2*w2b.y, 0.0f));
    ah[6] = f2bf(fmaxf(hs0*w0b.z + hs1*w1b.z + hs2*w2b.z, 0.0f));
    ah[7] = f2bf(fmaxf(hs0*w0b.w + hs1*w1b.w + hs2*w2b.w, 0.0f));
    bf16x8 aoB = __builtin_bit_cast(bf16x8, ao);
    bf16x8 ahB = __builtin_bit_cast(bf16x8, ah);
    #pragma unroll
    for (int nt = 0; nt < 10; ++nt) {
      ushort8 b1 = *(const ushort8*)&Bpan[nt*512 + L*8];
      ushort8 b2 = *(const ushort8*)&Bpan[(10 + nt)*512 + L*8];
      ac[nt] = __builtin_amdgcn_mfma_f32_16x16x32_bf16(aoB, __builtin_bit_cast(bf16x8, b1), ac[nt], 0, 0, 0);
      aw[nt] = __builtin_amdgcn_mfma_f32_16x16x32_bf16(ahB, __builtin_bit_cast(bf16x8, b2), aw[nt], 0, 0, 0);
    }
    if (kc < 7) {
      __syncthreads();   // all waves done reading Bpan for kc
      #pragma unroll
      for (int i = 0; i < 5; ++i) *(ushort8*)&Bpan[(wv*5 + i)*512 + L*8] = pf[i];
      __syncthreads();   // kc+1 panels visible
    }
  }

  int ebase = e0 + wv*16 + q4*4;
  int d0 = edst[ebase], d1 = edst[ebase+1], d2 = edst[ebase+2], d3 = edst[ebase+3];
  #pragma unroll
  for (int nt = 0; nt < 10; ++nt) {
    int col = nt*16 + m;
    atomicAdd(&x1[(size_t)d0*160 + col], ac[nt][0]*aw[nt][0]*INV_SQRT_NN);
    atomicAdd(&x1[(size_t)d1*160 + col], ac[nt][1]*aw[nt][1]*INV_SQRT_NN);
    atomicAdd(&x1[(size_t)d2*160 + col], ac[nt][2]*aw[nt][2]*INV_SQRT_NN);
    atomicAdd(&x1[(size_t)d3*160 + col], ac[nt][3]*aw[nt][3]*INV_SQRT_NN);
  }
}

// ---------------------------------------------------------------------------
// K3: gate  x1(N,160) -> x2bf(N,128) in bf16
// ---------------------------------------------------------------------------
__device__ __forceinline__ float gate_val(const float* xr, int o) {
  if (o < 16) return fmaxf(xr[o], 0.0f);
  if (o < 32) return fabsf(xr[o]);
  int oo = o - 32;
  int vi = oo / 3;
  float g = xr[32 + vi];
  g = (vi & 8) ? tanhf(g) : fmaxf(g, 0.0f);
  return xr[64 + oo] * g;
}

__global__ void k_gate(const float* __restrict__ x1, unsigned short* __restrict__ x2b) {
  int tid = blockIdx.x * 256 + threadIdx.x;
  if (tid >= NN*64) return;
  int n = tid >> 6, o2 = (tid & 63) * 2;
  const float* xr = x1 + (size_t)n * 160;
  ushort2 st;
  st.x = f2bf(gate_val(xr, o2));
  st.y = f2bf(gate_val(xr, o2 + 1));
  *(ushort2*)&x2b[(size_t)n*128 + o2] = st;
}

// ---------------------------------------------------------------------------
// K4: fused MLP2 + conv2 via MFMA (round-7 version: direct L2 B loads).
// ---------------------------------------------------------------------------
__global__ __launch_bounds__(256, 4) void k_conv2(
    const unsigned short* __restrict__ x2b, const float* __restrict__ shg,
    const float* __restrict__ scalg,
    const int* __restrict__ esrc, const int* __restrict__ edst,
    const float* __restrict__ W1b,
    const unsigned short* __restrict__ Bc2, const unsigned short* __restrict__ Bw2b,
    float* __restrict__ x3) {
  __shared__ float sh_lds[64*20];
  const int t = threadIdx.x;
  const int e0 = blockIdx.x * 64;
  {
    int e = t >> 2, q = t & 3;
    *(float4*)&sh_lds[e*20 + q*4] = ((const float4*)shg)[(size_t)(e0 + e)*4 + q];
  }
  __syncthreads();

  const int L = t & 63, wv = t >> 6;
  const int m = L & 15, q4 = L >> 4;
  const int el = wv*16 + m;
  const int ge = e0 + el;
  const int s_el = esrc[ge];
  float4 sc = ((const float4*)scalg)[ge];
  const float hs0 = sc.x*INV_SQRT3, hs1 = sc.y*INV_SQRT3, hs2 = sc.z*INV_SQRT3;

  f32x4 tAcc[7];
  #pragma unroll
  for (int nt = 0; nt < 7; ++nt) tAcc[nt] = (f32x4)(0.0f);
  f32x4 wAcc = (f32x4)(0.0f);

  const unsigned short* arow = x2b + (size_t)s_el*128 + q4*8;
  #pragma unroll
  for (int kc = 0; kc < 4; ++kc) {
    ushort8 a = *(const ushort8*)&arow[kc*32];
    bf16x8 aB = __builtin_bit_cast(bf16x8, a);
    #pragma unroll
    for (int nt = 0; nt < 7; ++nt) {
      ushort8 b = *(const ushort8*)&Bc2[(((size_t)nt*4 + kc)*64 + L)*8];
      tAcc[nt] = __builtin_amdgcn_mfma_f32_16x16x32_bf16(aB, __builtin_bit_cast(bf16x8, b), tAcc[nt], 0, 0, 0);
    }
  }
  #pragma unroll
  for (int kc = 0; kc < 8; ++kc) {
    int mh = kc*32 + q4*8;
    float4 w0a = *(const float4*)&W1b[mh];
    float4 w0b = *(const float4*)&W1b[mh + 4];
    float4 w1a = *(const float4*)&W1b[256 + mh];
    float4 w1b = *(const float4*)&W1b[256 + mh + 4];
    float4 w2a = *(const float4*)&W1b[512 + mh];
    float4 w2b = *(const float4*)&W1b[512 + mh + 4];
    ushort8 ah;
    ah[0] = f2bf(fmaxf(hs0*w0a.x + hs1*w1a.x + hs2*w2a.x, 0.0f));
    ah[1] = f2bf(fmaxf(hs0*w0a.y + hs1*w1a.y + hs2*w2a.y, 0.0f));
    ah[2] = f2bf(fmaxf(hs0*w0a.z + hs1*w1a.z + hs2*w2a.z, 0.0f));
    ah[3] = f2bf(fmaxf(hs0*w0a.w + hs1*w1a.w + hs2*w2a.w, 0.0f));
    ah[4] = f2bf(fmaxf(hs0*w0b.x + hs1*w1b.x + hs2*w2b.x, 0.0f));
    ah[5] = f2bf(fmaxf(hs0*w0b.y + hs1*w1b.y + hs2*w2b.y, 0.0f));
    ah[6] = f2bf(fmaxf(hs0*w0b.z + hs1*w1b.z + hs2*w2b.z, 0.0f));
    ah[7] = f2bf(fmaxf(hs0*w0b.w + hs1*w1b.w + hs2*w2b.w, 0.0f));
    ushort8 b = *(const ushort8*)&Bw2b[((size_t)kc*64 + L)*8];
    wAcc = __builtin_amdgcn_mfma_f32_16x16x32_bf16(
        __builtin_bit_cast(bf16x8, ah), __builtin_bit_cast(bf16x8, b), wAcc, 0, 0, 0);
  }

  int dsts[4];
  #pragma unroll
  for (int r = 0; r < 4; ++r) dsts[r] = edst[e0 + wv*16 + q4*4 + r];
  float ef[4] = {0.f, 0.f, 0.f, 0.f};
  #pragma unroll
  for (int nt = 0; nt < 7; ++nt) {
    #pragma unroll
    for (int r = 0; r < 4; ++r) {
      float v = tAcc[nt][r] * sh_lds[(wv*16 + q4*4 + r)*20 + m];
      v += __shfl_xor(v, 1);
      v += __shfl_xor(v, 2);
      v += __shfl_xor(v, 4);
      v += __shfl_xor(v, 8);
      if (m == nt) ef[r] = v;
    }
  }
  if (m < 7) {
    #pragma unroll
    for (int r = 0; r < 4; ++r)
      atomicAdd(&x3[(size_t)dsts[r]*7 + m], ef[r] * wAcc[r] * INV_SQRT_NN);
  }
}

// ---------------------------------------------------------------------------
// K5: graph readout  out[batch[n]] += x3[n] * 0.5
// ---------------------------------------------------------------------------
__global__ void k_out(const float* __restrict__ x3, const int* __restrict__ batch,
                      float* __restrict__ out) {
  int tid = blockIdx.x * 256 + threadIdx.x;
  if (tid >= NN*7) return;
  int n = tid / 7;
  int k = tid - n*7;
  atomicAdd(&out[batch[n]*7 + k], x3[tid] * 0.5f);
}

extern "C" void kernel_launch(void* const* d_in, const int* in_sizes, int n_in,
                              void* d_out, int out_size, void* d_ws, size_t ws_size,
                              hipStream_t stream) {
  const float* pos  = (const float*)d_in[0];
  const float* W1a  = (const float*)d_in[1];
  const float* W2a  = (const float*)d_in[2];
  const float* cg1  = (const float*)d_in[3];
  const float* W1b  = (const float*)d_in[4];
  const float* W2b  = (const float*)d_in[5];
  const float* cg2  = (const float*)d_in[6];
  const int* esrc   = (const int*)d_in[7];
  const int* edst   = (const int*)d_in[8];
  const int* batch  = (const int*)d_in[9];
  float* out = (float*)d_out;

  float* ws    = (float*)d_ws;
  float* shg   = ws;                       // NE*16
  float* scalg = shg   + (size_t)NE*16;    // NE*4
  float* x0    = scalg + (size_t)NE*4;     // NN*16
  float* x1    = x0    + (size_t)NN*16;    // NN*160
  float* x2g   = x1    + (size_t)NN*160;   // NN*128 slot (bf16 used)
  float* x3    = x2g   + (size_t)NN*128;   // NN*7
  unsigned short* x2b  = (unsigned short*)x2g;
  unsigned short* Bcg  = (unsigned short*)(x3 + (size_t)NN*7);  // 40960 bf16
  unsigned short* Bw2  = Bcg + 40960;                           // 40960 bf16
  unsigned short* Bc2  = Bw2 + 40960;                           // 14336 bf16
  unsigned short* Bw2b = Bc2 + 14336;                           // 4096 bf16

  hipMemsetAsync(x0, 0, sizeof(float)*(size_t)NN*16, stream);
  hipMemsetAsync(x1, 0, sizeof(float)*(size_t)NN*160, stream);
  hipMemsetAsync(x3, 0, sizeof(float)*(size_t)NN*7, stream);
  hipMemsetAsync(d_out, 0, sizeof(float)*NG*7, stream);

  k_prep <<<49, 256, 0, stream>>>(W2a, cg1, cg2, W2b, Bcg, Bw2, Bc2, Bw2b);
  k_edge <<<NE/256, 256, 0, stream>>>(pos, esrc, edst, shg, scalg, x0);
  k_conv1<<<NE/64, 256, 0, stream>>>(x0, shg, scalg, esrc, edst, W1a, Bcg, Bw2, x1);
  k_gate <<<(NN*64)/256, 256, 0, stream>>>(x1, x2b);
  k_conv2<<<NE/64, 256, 0, stream>>>(x2b, shg, scalg, esrc, edst, W1b, Bc2, Bw2b, x3);
  k_out  <<<(NN*7 + 255)/256, 256, 0, stream>>>(x3, batch, out);
}

// Round 11
// 495.291 us; speedup vs baseline: 1.3449x; 1.0311x over previous
//
#include <hip/hip_runtime.h>
#include <math.h>

#define NN 30000
#define NE 480000
#define NG 512

#define INV_SQRT_NN 0.5129891760425771f   // 1/sqrt(3.8)
#define INV_SQRT3   0.5773502691896258f   // 1/sqrt(3)
#define SCALE_W2    0.0625f               // 1/sqrt(256)
#define RAD_C       14.607377f            // 1.14136*e^2*sqrt(3)

typedef __bf16 bf16x8 __attribute__((ext_vector_type(8)));
typedef float f32x4 __attribute__((ext_vector_type(4)));
typedef unsigned short ushort8 __attribute__((ext_vector_type(8)));

__device__ __forceinline__ unsigned short f2bf(float f) {
  unsigned int u = __float_as_uint(f);
  return (unsigned short)((u + 0x7FFFu + ((u >> 16) & 1u)) >> 16);  // RNE
}

// ---------------------------------------------------------------------------
// K1: per-edge geometry -> sh(E,16), scal(E,4), x0 += sh (LDS-transposed scatter)
// ---------------------------------------------------------------------------
__global__ __launch_bounds__(256) void k_edge(
    const float* __restrict__ pos,
    const int* __restrict__ esrc,
    const int* __restrict__ edst,
    float* __restrict__ shg,
    float* __restrict__ scalg,
    float* __restrict__ x0) {
  __shared__ float S_lds[256*17];
  __shared__ int   d_lds[256];
  const int t = threadIdx.x;
  const int e = blockIdx.x * 256 + t;
  int s = esrc[e], d = edst[e];
  float ex = pos[3*s]   - pos[3*d];
  float ey = pos[3*s+1] - pos[3*d+1];
  float ez = pos[3*s+2] - pos[3*d+2];
  float r = sqrtf(ex*ex + ey*ey + ez*ez);
  float inv = 1.0f / fmaxf(r, 1e-9f);
  float x = ex*inv, y = ey*inv, z = ez*inv;
  float x2 = x*x, y2 = y*y, z2 = z*z;
  float S[16];
  S[0]  = 1.0f;
  S[1]  = 1.7320508075688772f * x;
  S[2]  = 1.7320508075688772f * y;
  S[3]  = 1.7320508075688772f * z;
  S[4]  = 3.872983346207417f * x * y;
  S[5]  = 3.872983346207417f * y * z;
  S[6]  = 1.118033988749895f * (3.0f*z2 - 1.0f);
  S[7]  = 3.872983346207417f * x * z;
  S[8]  = 1.9364916731037085f * (x2 - y2);
  S[9]  = 2.091650066335189f  * y * (3.0f*x2 - y2);
  S[10] = 10.246950765959598f * x * y * z;
  S[11] = 1.6201851746019651f * y * (5.0f*z2 - 1.0f);
  S[12] = 1.3228756555322954f * z * (5.0f*z2 - 3.0f);
  S[13] = 1.6201851746019651f * x * (5.0f*z2 - 1.0f);
  S[14] = 5.123475382979799f  * z * (x2 - y2);
  S[15] = 2.091650066335189f  * x * (x2 - y2);
  float4* shv = (float4*)(shg + (size_t)e * 16);
  shv[0] = make_float4(S[0],  S[1],  S[2],  S[3]);
  shv[1] = make_float4(S[4],  S[5],  S[6],  S[7]);
  shv[2] = make_float4(S[8],  S[9],  S[10], S[11]);
  shv[3] = make_float4(S[12], S[13], S[14], S[15]);
  float sc[3];
  #pragma unroll
  for (int c = 0; c < 3; ++c) {
    float v = 0.5f + (float)c;
    float uu = r - v;
    float dd = uu*uu - 1.0f;
    sc[c] = (dd < 0.0f) ? RAD_C * expf(1.0f/dd) : 0.0f;
  }
  ((float4*)scalg)[e] = make_float4(sc[0], sc[1], sc[2], 0.0f);

  d_lds[t] = d;
  #pragma unroll
  for (int j = 0; j < 16; ++j) S_lds[t*17 + j] = S[j];
  __syncthreads();
  #pragma unroll
  for (int it = 0; it < 16; ++it) {
    int idx = it*256 + t;
    int el = idx >> 4, j = idx & 15;
    atomicAdd(&x0[(size_t)d_lds[el]*16 + j], S_lds[el*17 + j]);
  }
}

// ---------------------------------------------------------------------------
// K_prep: convert all B-matrices to MFMA-fragment-ordered bf16 (unchanged).
// ---------------------------------------------------------------------------
__global__ void k_prep(const float* __restrict__ W2a, const float* __restrict__ cg1,
                       const float* __restrict__ cg2, const float* __restrict__ W2b,
                       unsigned short* __restrict__ Bcg, unsigned short* __restrict__ Bw2,
                       unsigned short* __restrict__ Bc2, unsigned short* __restrict__ Bw2b) {
  int tid = blockIdx.x * 256 + threadIdx.x;
  if (tid >= 12544) return;
  if (tid < 10240) {
    int sel = tid >= 5120;
    int t = sel ? tid - 5120 : tid;
    int lane = t & 63;
    int kc = (t >> 6) & 7;
    int nt = t >> 9;
    int n  = nt*16 + (lane & 15);
    int kb = kc*32 + (lane >> 4)*8;
    ushort8 v;
    if (!sel) {
      #pragma unroll
      for (int j = 0; j < 8; ++j) v[j] = f2bf(cg1[n*256 + kb + j]);
      *(ushort8*)&Bcg[(size_t)t*8] = v;
    } else {
      #pragma unroll
      for (int j = 0; j < 8; ++j) v[j] = f2bf(W2a[(kb + j)*160 + n] * SCALE_W2);
      *(ushort8*)&Bw2[(size_t)t*8] = v;
    }
  } else if (tid < 12032) {
    int et = tid - 10240;
    int L = et & 63;
    int kc = (et >> 6) & 3;
    int nt = et >> 8;
    int mcol = L & 15;
    int ib = kc*32 + (L >> 4)*8;
    ushort8 v;
    #pragma unroll
    for (int jj = 0; jj < 8; ++jj) v[jj] = f2bf(cg2[nt*2048 + (ib + jj)*16 + mcol]);
    *(ushort8*)&Bc2[(size_t)et*8] = v;
  } else {
    int et = tid - 12032;
    int L = et & 63;
    int kc = et >> 6;
    int mcol = L & 15;
    int ib = kc*32 + (L >> 4)*8;
    ushort8 v;
    #pragma unroll
    for (int jj = 0; jj < 8; ++jj)
      v[jj] = (mcol < 7) ? f2bf(W2b[(ib + jj)*7 + mcol] * SCALE_W2) : (unsigned short)0;
    *(ushort8*)&Bw2b[(size_t)et*8] = v;
  }
}

// ---------------------------------------------------------------------------
// K2: fused MLP1 + conv1 via MFMA + double-buffered LDS B-panels.
// EXACT round-7 configuration (best measured: 261us, VGPR 84, no spill).
// ---------------------------------------------------------------------------
__global__ __launch_bounds__(256, 2) void k_conv1(
    const float* __restrict__ x0, const float* __restrict__ shg,
    const float* __restrict__ scalg,
    const int* __restrict__ esrc, const int* __restrict__ edst,
    const float* __restrict__ W1a,
    const unsigned short* __restrict__ Bcg, const unsigned short* __restrict__ Bw2,
    float* __restrict__ x1) {
  __shared__ float sh_lds[64*20];
  __shared__ float xs_lds[64*20];
  __shared__ unsigned short Bpan[2][20*512];   // 2 bufs x 20 panels x 1KB = 40KB
  const int t = threadIdx.x;
  const int e0 = blockIdx.x * 64;

  {
    int e = t >> 2, q = t & 3;
    int ge = e0 + e;
    *(float4*)&sh_lds[e*20 + q*4] = ((const float4*)shg)[(size_t)ge*4 + q];
    float4 xv = ((const float4*)x0)[(size_t)esrc[ge]*4 + q];
    xv.x *= INV_SQRT_NN; xv.y *= INV_SQRT_NN; xv.z *= INV_SQRT_NN; xv.w *= INV_SQRT_NN;
    *(float4*)&xs_lds[e*20 + q*4] = xv;
  }
  const int L  = t & 63;
  const int wv = t >> 6;
  const int m  = L & 15;
  const int q4 = L >> 4;
  const int j0 = (q4 & 1) * 8;
  const int p  = q4 >> 1;
  const int el = wv*16 + m;

  const unsigned short* psrc[5];
  unsigned short* pdst0[5];
  #pragma unroll
  for (int i = 0; i < 5; ++i) {
    int pnl = wv*5 + i;
    int g = pnl >= 10;
    int nt = g ? pnl - 10 : pnl;
    psrc[i] = (g ? Bw2 : Bcg) + (((size_t)nt*8)*64 + L)*8;
    pdst0[i] = &Bpan[0][pnl*512 + L*8];
  }

  float4 sc = ((const float4*)scalg)[e0 + el];
  const float hs0 = sc.x*INV_SQRT3, hs1 = sc.y*INV_SQRT3, hs2 = sc.z*INV_SQRT3;

  ushort8 pf[5];
  #pragma unroll
  for (int i = 0; i < 5; ++i) pf[i] = *(const ushort8*)psrc[i];
  #pragma unroll
  for (int i = 0; i < 5; ++i) *(ushort8*)pdst0[i] = pf[i];
  __syncthreads();

  float sh8[8];
  *(float4*)&sh8[0] = *(float4*)&sh_lds[el*20 + j0];
  *(float4*)&sh8[4] = *(float4*)&sh_lds[el*20 + j0 + 4];
  float xsc[8];
  #pragma unroll
  for (int kc = 0; kc < 8; ++kc) xsc[kc] = xs_lds[el*20 + kc*2 + p];

  f32x4 ac[10], aw[10];
  #pragma unroll
  for (int i = 0; i < 10; ++i) {
    ac[i] = (f32x4)(0.0f);
    aw[i] = (f32x4)(0.0f);
  }

  #pragma unroll
  for (int kc = 0; kc < 8; ++kc) {
    if (kc < 7) {
      #pragma unroll
      for (int i = 0; i < 5; ++i) pf[i] = *(const ushort8*)(psrc[i] + (size_t)(kc+1)*512);
    }
    float xc = xsc[kc];
    ushort8 ao;
    #pragma unroll
    for (int j = 0; j < 8; ++j) ao[j] = f2bf(xc * sh8[j]);
    int mh = kc*32 + q4*8;
    float4 w0a = *(const float4*)&W1a[mh];
    float4 w0b = *(const float4*)&W1a[mh + 4];
    float4 w1a = *(const float4*)&W1a[256 + mh];
    float4 w1b = *(const float4*)&W1a[256 + mh + 4];
    float4 w2a = *(const float4*)&W1a[512 + mh];
    float4 w2b = *(const float4*)&W1a[512 + mh + 4];
    ushort8 ah;
    ah[0] = f2bf(fmaxf(hs0*w0a.x + hs1*w1a.x + hs2*w2a.x, 0.0f));
    ah[1] = f2bf(fmaxf(hs0*w0a.y + hs1*w1a.y + hs2*w2a.y, 0.0f));
    ah[2] = f2bf(fmaxf(hs0*w0a.z + hs1*w1a.z + hs2*w2a.z, 0.0f));
    ah[3] = f2bf(fmaxf(hs0*w0a.w + hs1*w1a.w + hs2*w2a.w, 0.0f));
    ah[4] = f2bf(fmaxf(hs0*w0b.x + hs1*w1b.x + hs2*w2b.x, 0.0f));
    ah[5] = f2bf(fmaxf(hs0*w0b.y + hs1*w1b.y + hs2*w2b.y, 0.0f));
    ah[6] = f2bf(fmaxf(hs0*w0b.z + hs1*w1b.z + hs2*w2b.z, 0.0f));
    ah[7] = f2bf(fmaxf(hs0*w0b.w + hs1*w1b.w + hs2*w2b.w, 0.0f));
    bf16x8 aoB = __builtin_bit_cast(bf16x8, ao);
    bf16x8 ahB = __builtin_bit_cast(bf16x8, ah);
    const unsigned short* buf = &Bpan[kc & 1][0];
    #pragma unroll
    for (int nt = 0; nt < 10; ++nt) {
      ushort8 b1 = *(const ushort8*)&buf[nt*512 + L*8];
      ushort8 b2 = *(const ushort8*)&buf[(10 + nt)*512 + L*8];
      ac[nt] = __builtin_amdgcn_mfma_f32_16x16x32_bf16(aoB, __builtin_bit_cast(bf16x8, b1), ac[nt], 0, 0, 0);
      aw[nt] = __builtin_amdgcn_mfma_f32_16x16x32_bf16(ahB, __builtin_bit_cast(bf16x8, b2), aw[nt], 0, 0, 0);
    }
    if (kc < 7) {
      unsigned short* dst = &Bpan[(kc + 1) & 1][0];
      #pragma unroll
      for (int i = 0; i < 5; ++i) *(ushort8*)(dst + (wv*5 + i)*512 + L*8) = pf[i];
      __syncthreads();
    }
  }

  int ebase = e0 + wv*16 + q4*4;
  int d0 = edst[ebase], d1 = edst[ebase+1], d2 = edst[ebase+2], d3 = edst[ebase+3];
  #pragma unroll
  for (int nt = 0; nt < 10; ++nt) {
    int col = nt*16 + m;
    atomicAdd(&x1[(size_t)d0*160 + col], ac[nt][0]*aw[nt][0]*INV_SQRT_NN);
    atomicAdd(&x1[(size_t)d1*160 + col], ac[nt][1]*aw[nt][1]*INV_SQRT_NN);
    atomicAdd(&x1[(size_t)d2*160 + col], ac[nt][2]*aw[nt][2]*INV_SQRT_NN);
    atomicAdd(&x1[(size_t)d3*160 + col], ac[nt][3]*aw[nt][3]*INV_SQRT_NN);
  }
}

// ---------------------------------------------------------------------------
// K3: gate  x1(N,160) -> x2bf(N,128) in bf16
// ---------------------------------------------------------------------------
__device__ __forceinline__ float gate_val(const float* xr, int o) {
  if (o < 16) return fmaxf(xr[o], 0.0f);
  if (o < 32) return fabsf(xr[o]);
  int oo = o - 32;
  int vi = oo / 3;
  float g = xr[32 + vi];
  g = (vi & 8) ? tanhf(g) : fmaxf(g, 0.0f);
  return xr[64 + oo] * g;
}

__global__ void k_gate(const float* __restrict__ x1, unsigned short* __restrict__ x2b) {
  int tid = blockIdx.x * 256 + threadIdx.x;
  if (tid >= NN*64) return;
  int n = tid >> 6, o2 = (tid & 63) * 2;
  const float* xr = x1 + (size_t)n * 160;
  ushort2 st;
  st.x = f2bf(gate_val(xr, o2));
  st.y = f2bf(gate_val(xr, o2 + 1));
  *(ushort2*)&x2b[(size_t)n*128 + o2] = st;
}

// ---------------------------------------------------------------------------
// K4: fused MLP2 + conv2 via MFMA, 2 M-tiles per wave (128 edges/block).
// Each B-fragment load feeds 2 MFMAs -> B L2 traffic halves (1.08GB->540MB).
// Acc = tAcc[2][7]+wAcc[2] = 64 VGPRs; launch_bounds(256,2) leaves the
// allocator 256 regs so no spill (the round-5 conv1 failure mode).
// ---------------------------------------------------------------------------
__global__ __launch_bounds__(256, 2) void k_conv2(
    const unsigned short* __restrict__ x2b, const float* __restrict__ shg,
    const float* __restrict__ scalg,
    const int* __restrict__ esrc, const int* __restrict__ edst,
    const float* __restrict__ W1b,
    const unsigned short* __restrict__ Bc2, const unsigned short* __restrict__ Bw2b,
    float* __restrict__ x3) {
  __shared__ float sh_lds[128*20];
  const int t = threadIdx.x;
  const int e0 = blockIdx.x * 128;
  #pragma unroll
  for (int i = 0; i < 2; ++i) {
    int idx = t + 256*i;
    int e = idx >> 2, q = idx & 3;
    *(float4*)&sh_lds[e*20 + q*4] = ((const float4*)shg)[(size_t)(e0 + e)*4 + q];
  }
  __syncthreads();

  const int L = t & 63, wv = t >> 6;
  const int m = L & 15, q4 = L >> 4;
  const int el0 = wv*32 + m;
  const int el1 = el0 + 16;
  const int s0 = esrc[e0 + el0];
  const int s1 = esrc[e0 + el1];
  float4 scA = ((const float4*)scalg)[e0 + el0];
  float4 scB = ((const float4*)scalg)[e0 + el1];
  const float hsA0 = scA.x*INV_SQRT3, hsA1 = scA.y*INV_SQRT3, hsA2 = scA.z*INV_SQRT3;
  const float hsB0 = scB.x*INV_SQRT3, hsB1 = scB.y*INV_SQRT3, hsB2 = scB.z*INV_SQRT3;

  f32x4 tAcc[2][7];
  #pragma unroll
  for (int tt = 0; tt < 2; ++tt)
    #pragma unroll
    for (int nt = 0; nt < 7; ++nt) tAcc[tt][nt] = (f32x4)(0.0f);
  f32x4 wAcc[2];
  wAcc[0] = (f32x4)(0.0f); wAcc[1] = (f32x4)(0.0f);

  const unsigned short* arow0 = x2b + (size_t)s0*128 + q4*8;
  const unsigned short* arow1 = x2b + (size_t)s1*128 + q4*8;
  #pragma unroll
  for (int kc = 0; kc < 4; ++kc) {
    ushort8 a0 = *(const ushort8*)&arow0[kc*32];
    ushort8 a1 = *(const ushort8*)&arow1[kc*32];
    bf16x8 a0B = __builtin_bit_cast(bf16x8, a0);
    bf16x8 a1B = __builtin_bit_cast(bf16x8, a1);
    #pragma unroll
    for (int nt = 0; nt < 7; ++nt) {
      ushort8 b = *(const ushort8*)&Bc2[(((size_t)nt*4 + kc)*64 + L)*8];
      bf16x8 bB = __builtin_bit_cast(bf16x8, b);
      tAcc[0][nt] = __builtin_amdgcn_mfma_f32_16x16x32_bf16(a0B, bB, tAcc[0][nt], 0, 0, 0);
      tAcc[1][nt] = __builtin_amdgcn_mfma_f32_16x16x32_bf16(a1B, bB, tAcc[1][nt], 0, 0, 0);
    }
  }
  #pragma unroll
  for (int kc = 0; kc < 8; ++kc) {
    int mh = kc*32 + q4*8;
    float4 w0a = *(const float4*)&W1b[mh];
    float4 w0b = *(const float4*)&W1b[mh + 4];
    float4 w1a = *(const float4*)&W1b[256 + mh];
    float4 w1b = *(const float4*)&W1b[256 + mh + 4];
    float4 w2a = *(const float4*)&W1b[512 + mh];
    float4 w2b = *(const float4*)&W1b[512 + mh + 4];
    ushort8 ahA, ahB;
    ahA[0] = f2bf(fmaxf(hsA0*w0a.x + hsA1*w1a.x + hsA2*w2a.x, 0.0f));
    ahA[1] = f2bf(fmaxf(hsA0*w0a.y + hsA1*w1a.y + hsA2*w2a.y, 0.0f));
    ahA[2] = f2bf(fmaxf(hsA0*w0a.z + hsA1*w1a.z + hsA2*w2a.z, 0.0f));
    ahA[3] = f2bf(fmaxf(hsA0*w0a.w + hsA1*w1a.w + hsA2*w2a.w, 0.0f));
    ahA[4] = f2bf(fmaxf(hsA0*w0b.x + hsA1*w1b.x + hsA2*w2b.x, 0.0f));
    ahA[5] = f2bf(fmaxf(hsA0*w0b.y + hsA1*w1b.y + hsA2*w2b.y, 0.0f));
    ahA[6] = f2bf(fmaxf(hsA0*w0b.z + hsA1*w1b.z + hsA2*w2b.z, 0.0f));
    ahA[7] = f2bf(fmaxf(hsA0*w0b.w + hsA1*w1b.w + hsA2*w2b.w, 0.0f));
    ahB[0] = f2bf(fmaxf(hsB0*w0a.x + hsB1*w1a.x + hsB2*w2a.x, 0.0f));
    ahB[1] = f2bf(fmaxf(hsB0*w0a.y + hsB1*w1a.y + hsB2*w2a.y, 0.0f));
    ahB[2] = f2bf(fmaxf(hsB0*w0a.z + hsB1*w1a.z + hsB2*w2a.z, 0.0f));
    ahB[3] = f2bf(fmaxf(hsB0*w0a.w + hsB1*w1a.w + hsB2*w2a.w, 0.0f));
    ahB[4] = f2bf(fmaxf(hsB0*w0b.x + hsB1*w1b.x + hsB2*w2b.x, 0.0f));
    ahB[5] = f2bf(fmaxf(hsB0*w0b.y + hsB1*w1b.y + hsB2*w2b.y, 0.0f));
    ahB[6] = f2bf(fmaxf(hsB0*w0b.z + hsB1*w1b.z + hsB2*w2b.z, 0.0f));
    ahB[7] = f2bf(fmaxf(hsB0*w0b.w + hsB1*w1b.w + hsB2*w2b.w, 0.0f));
    ushort8 b = *(const ushort8*)&Bw2b[((size_t)kc*64 + L)*8];
    bf16x8 bB = __builtin_bit_cast(bf16x8, b);
    wAcc[0] = __builtin_amdgcn_mfma_f32_16x16x32_bf16(__builtin_bit_cast(bf16x8, ahA), bB, wAcc[0], 0, 0, 0);
    wAcc[1] = __builtin_amdgcn_mfma_f32_16x16x32_bf16(__builtin_bit_cast(bf16x8, ahB), bB, wAcc[1], 0, 0, 0);
  }

  #pragma unroll
  for (int tt = 0; tt < 2; ++tt) {
    int base = wv*32 + tt*16 + q4*4;
    int dsts[4];
    #pragma unroll
    for (int r = 0; r < 4; ++r) dsts[r] = edst[e0 + base + r];
    float ef[4] = {0.f, 0.f, 0.f, 0.f};
    #pragma unroll
    for (int nt = 0; nt < 7; ++nt) {
      #pragma unroll
      for (int r = 0; r < 4; ++r) {
        float v = tAcc[tt][nt][r] * sh_lds[(base + r)*20 + m];
        v += __shfl_xor(v, 1);
        v += __shfl_xor(v, 2);
        v += __shfl_xor(v, 4);
        v += __shfl_xor(v, 8);
        if (m == nt) ef[r] = v;
      }
    }
    if (m < 7) {
      #pragma unroll
      for (int r = 0; r < 4; ++r)
        atomicAdd(&x3[(size_t)dsts[r]*7 + m], ef[r] * wAcc[tt][r] * INV_SQRT_NN);
    }
  }
}

// ---------------------------------------------------------------------------
// K5: graph readout  out[batch[n]] += x3[n] * 0.5
// ---------------------------------------------------------------------------
__global__ void k_out(const float* __restrict__ x3, const int* __restrict__ batch,
                      float* __restrict__ out) {
  int tid = blockIdx.x * 256 + threadIdx.x;
  if (tid >= NN*7) return;
  int n = tid / 7;
  int k = tid - n*7;
  atomicAdd(&out[batch[n]*7 + k], x3[tid] * 0.5f);
}

extern "C" void kernel_launch(void* const* d_in, const int* in_sizes, int n_in,
                              void* d_out, int out_size, void* d_ws, size_t ws_size,
                              hipStream_t stream) {
  const float* pos  = (const float*)d_in[0];
  const float* W1a  = (const float*)d_in[1];
  const float* W2a  = (const float*)d_in[2];
  const float* cg1  = (const float*)d_in[3];
  const float* W1b  = (const float*)d_in[4];
  const float* W2b  = (const float*)d_in[5];
  const float* cg2  = (const float*)d_in[6];
  const int* esrc   = (const int*)d_in[7];
  const int* edst   = (const int*)d_in[8];
  const int* batch  = (const int*)d_in[9];
  float* out = (float*)d_out;

  float* ws    = (float*)d_ws;
  float* shg   = ws;                       // NE*16
  float* scalg = shg   + (size_t)NE*16;    // NE*4
  float* x0    = scalg + (size_t)NE*4;     // NN*16
  float* x1    = x0    + (size_t)NN*16;    // NN*160
  float* x2g   = x1    + (size_t)NN*160;   // NN*128 slot (bf16 used)
  float* x3    = x2g   + (size_t)NN*128;   // NN*7
  unsigned short* x2b  = (unsigned short*)x2g;
  unsigned short* Bcg  = (unsigned short*)(x3 + (size_t)NN*7);  // 40960 bf16
  unsigned short* Bw2  = Bcg + 40960;                           // 40960 bf16
  unsigned short* Bc2  = Bw2 + 40960;                           // 14336 bf16
  unsigned short* Bw2b = Bc2 + 14336;                           // 4096 bf16

  hipMemsetAsync(x0, 0, sizeof(float)*(size_t)NN*16, stream);
  hipMemsetAsync(x1, 0, sizeof(float)*(size_t)NN*160, stream);
  hipMemsetAsync(x3, 0, sizeof(float)*(size_t)NN*7, stream);
  hipMemsetAsync(d_out, 0, sizeof(float)*NG*7, stream);

  k_prep <<<49, 256, 0, stream>>>(W2a, cg1, cg2, W2b, Bcg, Bw2, Bc2, Bw2b);
  k_edge <<<NE/256, 256, 0, stream>>>(pos, esrc, edst, shg, scalg, x0);
  k_conv1<<<NE/64, 256, 0, stream>>>(x0, shg, scalg, esrc, edst, W1a, Bcg, Bw2, x1);
  k_gate <<<(NN*64)/256, 256, 0, stream>>>(x1, x2b);
  k_conv2<<<NE/128, 256, 0, stream>>>(x2b, shg, scalg, esrc, edst, W1b, Bc2, Bw2b, x3);
  k_out  <<<(NN*7 + 255)/256, 256, 0, stream>>>(x3, batch, out);
}